// Round 3
// baseline (311.042 us; speedup 1.0000x reference)
//
#include <hip/hip_runtime.h>
#include <math.h>

// Problem constants
#define B_ 2
#define M_ 4
#define C_ 64
#define V_ 110592   // 48*48*48
#define EPS_ 1e-6f

// Workspace layout (floats) — every slot written every call (no memset):
//   P_NUM : num partials [bm(8)][c(64)][s(8)][k(4)] = 16384
//   P_TW  : tw partials  [bm(8)][s(8)][k(4)]        = 256
//   P_CNT : cnt partials [b(2)][s(8)][k(4)]         = 64
#define P_NUM 0
#define P_TW  16384
#define P_CNT 16640
#define NS_   8          // V-chunks

__constant__ int PM_[6] = {0,0,0,1,1,2};
__constant__ int PN_[6] = {1,2,3,2,3,3};

typedef float fvec4 __attribute__((ext_vector_type(4)));

// ---------------------------------------------------------------------------
// Main kernel: fused stats + num partials.
// grid = bm(8) x ch(16) x s(8) = 1024 blocks, 256 threads.
// Each block: channels {ch, ch+16, ch+32, ch+48}, V-chunk s (1/8 of V).
// ch==0 blocks additionally produce tw/count partials.
// ---------------------------------------------------------------------------
__global__ __launch_bounds__(256) void main_kernel(
    const float* __restrict__ f, const float* __restrict__ w,
    const int* __restrict__ tgt, float* __restrict__ ws)
{
    int idx = blockIdx.x;
    int s  = idx & 7;
    int ch = (idx >> 3) & 15;
    int bm = idx >> 7;
    int b  = bm >> 2;
    const bool do_stats = (ch == 0);

    const int chunk = (V_ / 4) / NS_;   // 3456 float4 per s-chunk

    const fvec4* f0 = (const fvec4*)(f + ((size_t)bm * C_ + ch     ) * V_);
    const fvec4* f1 = (const fvec4*)(f + ((size_t)bm * C_ + ch + 16) * V_);
    const fvec4* f2 = (const fvec4*)(f + ((size_t)bm * C_ + ch + 32) * V_);
    const fvec4* f3 = (const fvec4*)(f + ((size_t)bm * C_ + ch + 48) * V_);
    const float4* w4 = (const float4*)(w + (size_t)bm * V_);
    const int4*   t4 = (const int4*)(tgt + (size_t)b * V_);

    float A[16];
    #pragma unroll
    for (int j = 0; j < 16; ++j) A[j] = 0.f;
    float tw[4] = {0,0,0,0};
    int   cn[4] = {0,0,0,0};

    int beg = s * chunk, end = beg + chunk;
    for (int i = beg + (int)threadIdx.x; i < end; i += 256) {
        fvec4  v0 = __builtin_nontemporal_load(&f0[i]);
        fvec4  v1 = __builtin_nontemporal_load(&f1[i]);
        fvec4  v2 = __builtin_nontemporal_load(&f2[i]);
        fvec4  v3 = __builtin_nontemporal_load(&f3[i]);
        float4 wv = w4[i];
        int4   kv = t4[i];
        float p00 = v0.x*wv.x, p01 = v0.y*wv.y, p02 = v0.z*wv.z, p03 = v0.w*wv.w;
        float p10 = v1.x*wv.x, p11 = v1.y*wv.y, p12 = v1.z*wv.z, p13 = v1.w*wv.w;
        float p20 = v2.x*wv.x, p21 = v2.y*wv.y, p22 = v2.z*wv.z, p23 = v2.w*wv.w;
        float p30 = v3.x*wv.x, p31 = v3.y*wv.y, p32 = v3.z*wv.z, p33 = v3.w*wv.w;
        #pragma unroll
        for (int k = 0; k < 4; ++k) {
            A[k]      += (kv.x==k?p00:0.f) + (kv.y==k?p01:0.f) + (kv.z==k?p02:0.f) + (kv.w==k?p03:0.f);
            A[4 + k]  += (kv.x==k?p10:0.f) + (kv.y==k?p11:0.f) + (kv.z==k?p12:0.f) + (kv.w==k?p13:0.f);
            A[8 + k]  += (kv.x==k?p20:0.f) + (kv.y==k?p21:0.f) + (kv.z==k?p22:0.f) + (kv.w==k?p23:0.f);
            A[12 + k] += (kv.x==k?p30:0.f) + (kv.y==k?p31:0.f) + (kv.z==k?p32:0.f) + (kv.w==k?p33:0.f);
        }
        if (do_stats) {
            #pragma unroll
            for (int k = 0; k < 4; ++k) {
                tw[k] += (kv.x==k?wv.x:0.f) + (kv.y==k?wv.y:0.f) + (kv.z==k?wv.z:0.f) + (kv.w==k?wv.w:0.f);
                cn[k] += (kv.x==k) + (kv.y==k) + (kv.z==k) + (kv.w==k);
            }
        }
    }

    // wave(64) shuffle reduce
    #pragma unroll
    for (int off = 32; off; off >>= 1) {
        #pragma unroll
        for (int j = 0; j < 16; ++j) A[j] += __shfl_down(A[j], off);
        if (do_stats) {
            #pragma unroll
            for (int k = 0; k < 4; ++k) {
                tw[k] += __shfl_down(tw[k], off);
                cn[k] += __shfl_down(cn[k], off);
            }
        }
    }

    __shared__ float sA[4][16];
    __shared__ float sT[4][4];
    __shared__ int   sC[4][4];
    int wid = threadIdx.x >> 6, lane = threadIdx.x & 63;
    if (lane == 0) {
        #pragma unroll
        for (int j = 0; j < 16; ++j) sA[wid][j] = A[j];
        if (do_stats) {
            #pragma unroll
            for (int k = 0; k < 4; ++k) { sT[wid][k] = tw[k]; sC[wid][k] = cn[k]; }
        }
    }
    __syncthreads();

    if (threadIdx.x < 16) {
        int j = threadIdx.x;
        int k = j & 3;
        int c = ch + (j >> 2) * 16;
        float v = sA[0][j] + sA[1][j] + sA[2][j] + sA[3][j];
        ws[P_NUM + ((bm * C_ + c) * NS_ + s) * 4 + k] = v;
    }
    if (do_stats && threadIdx.x < 4) {
        int k = threadIdx.x;
        float t = sT[0][k] + sT[1][k] + sT[2][k] + sT[3][k];
        ws[P_TW + (bm * NS_ + s) * 4 + k] = t;
        if ((bm & 3) == 0) {
            int cc = sC[0][k] + sC[1][k] + sC[2][k] + sC[3][k];
            ws[P_CNT + (b * NS_ + s) * 4 + k] = (float)cc;
        }
    }
}

// ---------------------------------------------------------------------------
// Finalize: sum partials, prototypes, normalize, align/sep, scalar out.
// one block, 256 threads.
// ---------------------------------------------------------------------------
__global__ __launch_bounds__(256) void finalize_kernel(
    const float* __restrict__ ws, float* __restrict__ out)
{
    __shared__ float sp[2048];          // proto [32][64]
    __shared__ float s_tw[32];
    __shared__ float s_cnt[8];
    __shared__ float s_scale[32];
    __shared__ float s_om[32];
    __shared__ int   s_valid[32];

    int tid = threadIdx.x;

    if (tid < 32) {                     // tw[bm][k]
        int bm = tid >> 2, k = tid & 3;
        float t = 0.f;
        #pragma unroll
        for (int s = 0; s < NS_; ++s) t += ws[P_TW + (bm * NS_ + s) * 4 + k];
        s_tw[tid] = t;
    } else if (tid < 40) {              // cnt[b][k]
        int u = tid - 32, b = u >> 2, k = u & 3;
        float t = 0.f;
        #pragma unroll
        for (int s = 0; s < NS_; ++s) t += ws[P_CNT + (b * NS_ + s) * 4 + k];
        s_cnt[u] = t;
    }
    __syncthreads();

    // raw proto = num / (tw + EPS);  num[bm][k][c] = sum_s partial[bm][c][s][k]
    for (int i = tid; i < 2048; i += 256) {
        int p = i >> 6, c = i & 63;
        int bm = p >> 2, k = p & 3;
        float t = 0.f;
        #pragma unroll
        for (int s = 0; s < NS_; ++s) t += ws[P_NUM + ((bm * C_ + c) * NS_ + s) * 4 + k];
        sp[i] = t / (s_tw[p] + EPS_);
    }
    __syncthreads();

    if (tid < 32) {
        float ss = 0.f;
        for (int c = 0; c < 64; ++c) { float v = sp[tid * 64 + c]; ss += v * v; }
        float norm = sqrtf(fmaxf(ss, 1e-24f));          // NORM_EPS^2
        s_scale[tid] = 1.0f / fmaxf(norm, 1e-12f);
        int b = tid >> 4, k = tid & 3;
        float cc = s_cnt[b * 4 + k];
        s_om[tid] = (s_tw[tid] + EPS_) / (cc + EPS_);
        s_valid[tid] = (cc >= 1.0f) && (k != 0);
    }
    __syncthreads();
    for (int i = tid; i < 2048; i += 256) sp[i] *= s_scale[i >> 6];
    __syncthreads();

    float aS = 0.f, aC = 0.f, sS = 0.f, sC = 0.f;

    if (tid < 48) {                     // align: b(2) x mn-pair(6) x k(4)
        int b = tid / 24, r = tid % 24;
        int pr = r >> 2, k = r & 3;
        int p1 = (b * 4 + PM_[pr]) * 4 + k;
        int p2 = (b * 4 + PN_[pr]) * 4 + k;
        if (s_valid[p1] && s_valid[p2]) {
            float d = 0.f;
            for (int c = 0; c < 64; ++c) d += sp[p1 * 64 + c] * sp[p2 * 64 + c];
            aS = s_om[p1] * s_om[p2] * fmaxf(0.9f - d, 0.f);
            aC = 1.f;
        }
    } else if (tid >= 64 && tid < 112) { // sep: b(2) x m(4) x kl-pair(6)
        int t = tid - 64;
        int b = t / 24, r = t % 24;
        int m = r / 6, pr = r % 6;
        int bm = b * 4 + m;
        int p1 = bm * 4 + PM_[pr];
        int p2 = bm * 4 + PN_[pr];
        if (s_valid[p1] && s_valid[p2]) {
            float d = 0.f;
            for (int c = 0; c < 64; ++c) d += sp[p1 * 64 + c] * sp[p2 * 64 + c];
            sS = fmaxf(d - 0.1f, 0.f);
            sC = 1.f;
        }
    }

    #pragma unroll
    for (int off = 32; off; off >>= 1) {
        aS += __shfl_down(aS, off); aC += __shfl_down(aC, off);
        sS += __shfl_down(sS, off); sC += __shfl_down(sC, off);
    }
    __shared__ float red[4][4];
    int wid = tid >> 6, lane = tid & 63;
    if (lane == 0) { red[wid][0]=aS; red[wid][1]=aC; red[wid][2]=sS; red[wid][3]=sC; }
    __syncthreads();
    if (tid == 0) {
        float AS=0.f, AC=0.f, SS=0.f, SC=0.f;
        #pragma unroll
        for (int i = 0; i < 4; ++i) { AS+=red[i][0]; AC+=red[i][1]; SS+=red[i][2]; SC+=red[i][3]; }
        out[0] = AS / (AC + EPS_) + SS / (SC + EPS_);
    }
}

extern "C" void kernel_launch(void* const* d_in, const int* in_sizes, int n_in,
                              void* d_out, int out_size, void* d_ws, size_t ws_size,
                              hipStream_t stream)
{
    const float* feats   = (const float*)d_in[0];
    const float* weights = (const float*)d_in[1];
    const int*   target  = (const int*)d_in[2];
    float* out = (float*)d_out;
    float* ws  = (float*)d_ws;

    main_kernel<<<B_*16*NS_*M_, 256, 0, stream>>>(feats, weights, target, ws);
    finalize_kernel<<<1, 256, 0, stream>>>(ws, out);
}